// Round 6
// baseline (366.898 us; speedup 1.0000x reference)
//
#include <hip/hip_runtime.h>

// Problem: out = u2 + trilinear(u1, grid + u2); B=2, D=H=W=160, C=3, fp32.
constexpr int Bn = 2;
constexpr int Dn = 160;
constexpr int Hn = 160;
constexpr int Wn = 160;
constexpr int NV  = Bn * Dn * Hn * Wn;         // 8,192,000 voxels
constexpr int VOL = Dn * Hn * Wn;              // 4,096,000 voxels / batch

constexpr int TPB  = 256;
constexpr int NBLK = NV / TPB;                 // 32000 blocks (exact)
constexpr int NXCD = 8;
constexpr int CHUNK = NBLK / NXCD;             // 4000 blocks per XCD chunk

// 16B vector with 8B alignment guarantee: row base is aligned down to 8B
// (B = R & ~7), which is PROVABLE to the backend -> it keeps the
// global_load_dwordx4 whole instead of splitting to scalars (R5 failure:
// 4B-aligned unaligned vectors were split; VGPR stayed 24).
typedef float f32x4a8 __attribute__((ext_vector_type(4), aligned(8)));

__global__ __launch_bounds__(TPB) void compose_transform_kernel(
    const float* __restrict__ warp1,
    const float* __restrict__ warp2,
    float* __restrict__ out) {

    // XCD-chunked swizzle (proven: FETCH 389->100 MB). Bijective since
    // NBLK % NXCD == 0.
    int bid = blockIdx.x;
    int swz = (bid & (NXCD - 1)) * CHUNK + (bid >> 3);

    int idx = swz * TPB + (int)threadIdx.x;    // voxel id over B*D*H*W

    // decode (b, d, h, w)
    int w  = idx % Wn;
    int t  = idx / Wn;
    int h  = t % Hn;
    t      = t / Hn;
    int d  = t % Dn;
    int b  = t / Dn;

    int base3 = idx * 3;
    // streaming read — nontemporal to keep L2/L3 for the warp1 gathers
    float u2x = __builtin_nontemporal_load(warp2 + base3 + 0);
    float u2y = __builtin_nontemporal_load(warp2 + base3 + 1);
    float u2z = __builtin_nontemporal_load(warp2 + base3 + 2);

    // loc = grid + u2, clipped to [0, size-1]
    float lx = fminf(fmaxf((float)d + u2x, 0.0f), (float)(Dn - 1));
    float ly = fminf(fmaxf((float)h + u2y, 0.0f), (float)(Hn - 1));
    float lz = fminf(fmaxf((float)w + u2z, 0.0f), (float)(Wn - 1));

    // Border-remapped bases: ixb in [0, size-2]; the clamped duplicate corner
    // gets full weight — matches i1=min(i0+1,..) reference semantics exactly.
    int ixb = min((int)floorf(lx), Dn - 2);
    int iyb = min((int)floorf(ly), Hn - 2);
    int izb = min((int)floorf(lz), Wn - 2);

    float wx1 = lx - (float)ixb, wx0 = 1.0f - wx1;
    float wy1 = ly - (float)iyb, wy0 = 1.0f - wy1;
    float wz1 = lz - (float)izb, wz0 = 1.0f - wz1;

    // Row-start byte offsets (always multiples of 12 -> = 0 mod 4).
    // Max row start = 97,996,776; +32B read stays far inside the
    // 98,304,000 B buffer -> no end clamp needed.
    unsigned vbase = (unsigned)b * (unsigned)(VOL * 12);
    unsigned R00 = vbase + (unsigned)(((ixb * Hn + iyb) * Wn + izb) * 12);
    unsigned R01 = R00 + (unsigned)(Wn * 12);          // +1920  (mult of 8)
    unsigned R10 = R00 + (unsigned)(Hn * Wn * 12);     // +307200 (mult of 8)
    unsigned R11 = R10 + (unsigned)(Wn * 12);

    // All four rows share the same 8B-phase: k = (R00>>2)&1. Row floats are
    // vv[k..k+5] of the 8 dwords loaded from the aligned-down base.
    bool k1 = (R00 & 4u) != 0u;

    const char* w1b = reinterpret_cast<const char*>(warp1);
    const f32x4a8* q00 = reinterpret_cast<const f32x4a8*>(w1b + (R00 & ~7u));
    const f32x4a8* q01 = reinterpret_cast<const f32x4a8*>(w1b + (R01 & ~7u));
    const f32x4a8* q10 = reinterpret_cast<const f32x4a8*>(w1b + (R10 & ~7u));
    const f32x4a8* q11 = reinterpret_cast<const f32x4a8*>(w1b + (R11 & ~7u));

    // Issue all 8 dwordx4 gather loads before any use — max loads in flight.
    f32x4a8 lo00 = q00[0], hi00 = q00[1];
    f32x4a8 lo01 = q01[0], hi01 = q01[1];
    f32x4a8 lo10 = q10[0], hi10 = q10[1];
    f32x4a8 lo11 = q11[0], hi11 = q11[1];

    float w00 = wx0 * wy0;
    float w01 = wx0 * wy1;
    float w10 = wx1 * wy0;
    float w11 = wx1 * wy1;

    float c0x, c0y, c0z, c1x, c1y, c1z;
    float rx, ry, rz;
    float accx, accy, accz;

    // row 00: vv = {lo.xyzw, hi.xyzw}; row floats vv[k..k+5]
    c0x = k1 ? lo00.y : lo00.x;
    c0y = k1 ? lo00.z : lo00.y;
    c0z = k1 ? lo00.w : lo00.z;
    c1x = k1 ? hi00.x : lo00.w;
    c1y = k1 ? hi00.y : hi00.x;
    c1z = k1 ? hi00.z : hi00.y;
    rx = fmaf(wz1, c1x, wz0 * c0x);
    ry = fmaf(wz1, c1y, wz0 * c0y);
    rz = fmaf(wz1, c1z, wz0 * c0z);
    accx = w00 * rx; accy = w00 * ry; accz = w00 * rz;

    // row 01
    c0x = k1 ? lo01.y : lo01.x;
    c0y = k1 ? lo01.z : lo01.y;
    c0z = k1 ? lo01.w : lo01.z;
    c1x = k1 ? hi01.x : lo01.w;
    c1y = k1 ? hi01.y : hi01.x;
    c1z = k1 ? hi01.z : hi01.y;
    rx = fmaf(wz1, c1x, wz0 * c0x);
    ry = fmaf(wz1, c1y, wz0 * c0y);
    rz = fmaf(wz1, c1z, wz0 * c0z);
    accx = fmaf(w01, rx, accx); accy = fmaf(w01, ry, accy); accz = fmaf(w01, rz, accz);

    // row 10
    c0x = k1 ? lo10.y : lo10.x;
    c0y = k1 ? lo10.z : lo10.y;
    c0z = k1 ? lo10.w : lo10.z;
    c1x = k1 ? hi10.x : lo10.w;
    c1y = k1 ? hi10.y : hi10.x;
    c1z = k1 ? hi10.z : hi10.y;
    rx = fmaf(wz1, c1x, wz0 * c0x);
    ry = fmaf(wz1, c1y, wz0 * c0y);
    rz = fmaf(wz1, c1z, wz0 * c0z);
    accx = fmaf(w10, rx, accx); accy = fmaf(w10, ry, accy); accz = fmaf(w10, rz, accz);

    // row 11
    c0x = k1 ? lo11.y : lo11.x;
    c0y = k1 ? lo11.z : lo11.y;
    c0z = k1 ? lo11.w : lo11.z;
    c1x = k1 ? hi11.x : lo11.w;
    c1y = k1 ? hi11.y : hi11.x;
    c1z = k1 ? hi11.z : hi11.y;
    rx = fmaf(wz1, c1x, wz0 * c0x);
    ry = fmaf(wz1, c1y, wz0 * c0y);
    rz = fmaf(wz1, c1z, wz0 * c0z);
    accx = fmaf(w11, rx, accx); accy = fmaf(w11, ry, accy); accz = fmaf(w11, rz, accz);

    // streaming write — scalar nontemporal (WRITE_SIZE exactly 96000 KB)
    __builtin_nontemporal_store(u2x + accx, out + base3 + 0);
    __builtin_nontemporal_store(u2y + accy, out + base3 + 1);
    __builtin_nontemporal_store(u2z + accz, out + base3 + 2);
}

extern "C" void kernel_launch(void* const* d_in, const int* in_sizes, int n_in,
                              void* d_out, int out_size, void* d_ws, size_t ws_size,
                              hipStream_t stream) {
    const float* warp1 = (const float*)d_in[0];
    const float* warp2 = (const float*)d_in[1];
    float* out = (float*)d_out;

    compose_transform_kernel<<<NBLK, TPB, 0, stream>>>(warp1, warp2, out);
}